// Round 2
// baseline (853.017 us; speedup 1.0000x reference)
//
#include <hip/hip_runtime.h>
#include <math.h>

#define H 4096
#define TWO_H 8192
#define FIVE_H 20480
#define EPS 1e-5f

typedef float v4f __attribute__((ext_vector_type(4)));

// ---------------------------------------------------------------------------
// Kernel 1: z[row] = dot(W[row, :], concat(h0, h1)) for row in [0, 5H)
// One wave per 2 consecutive rows (x float4 reused across the pair).
// Pure streaming: lane reads W[row] at i*64+lane (fully coalesced float4),
// nontemporal (W has zero reuse -> don't thrash L1/L2; x stays cache-hot).
// Low VGPR -> max occupancy -> enough in-flight loads to cover HBM latency.
// ---------------------------------------------------------------------------
__global__ __launch_bounds__(256) void matvec_kernel(
    const float* __restrict__ W, const float* __restrict__ h0,
    const float* __restrict__ h1, float* __restrict__ z) {
  const int tid = threadIdx.x;
  const int lane = tid & 63;
  const int wv = tid >> 6;
  const int row0 = blockIdx.x * 8 + wv * 2;  // 4 waves/block * 2 rows

  const v4f* __restrict__ Wa = (const v4f*)(W + (size_t)row0 * TWO_H);
  const v4f* __restrict__ Wb = Wa + (TWO_H / 4);  // next row
  const v4f* __restrict__ x0 = (const v4f*)h0;
  const v4f* __restrict__ x1 = (const v4f*)h1;

  float acc0 = 0.f, acc1 = 0.f;

  // First half: x = h0 (float4 indices [0, 1024))
#pragma unroll 4
  for (int i = 0; i < 16; ++i) {
    const int idx = i * 64 + lane;
    v4f xv = x0[idx];
    v4f wa = __builtin_nontemporal_load(&Wa[idx]);
    v4f wb = __builtin_nontemporal_load(&Wb[idx]);
    acc0 += wa[0] * xv[0] + wa[1] * xv[1] + wa[2] * xv[2] + wa[3] * xv[3];
    acc1 += wb[0] * xv[0] + wb[1] * xv[1] + wb[2] * xv[2] + wb[3] * xv[3];
  }
  // Second half: x = h1 (W float4 indices [1024, 2048))
#pragma unroll 4
  for (int i = 0; i < 16; ++i) {
    const int idx = i * 64 + lane;
    const int widx = idx + 1024;
    v4f xv = x1[idx];
    v4f wa = __builtin_nontemporal_load(&Wa[widx]);
    v4f wb = __builtin_nontemporal_load(&Wb[widx]);
    acc0 += wa[0] * xv[0] + wa[1] * xv[1] + wa[2] * xv[2] + wa[3] * xv[3];
    acc1 += wb[0] * xv[0] + wb[1] * xv[1] + wb[2] * xv[2] + wb[3] * xv[3];
  }

  // Wave-level tree reduce (64 lanes)
#pragma unroll
  for (int off = 32; off; off >>= 1) {
    acc0 += __shfl_down(acc0, off, 64);
    acc1 += __shfl_down(acc1, off, 64);
  }
  if (lane == 0) {
    z[row0] = acc0;
    z[row0 + 1] = acc1;
  }
}

// ---------------------------------------------------------------------------
// Kernel 2: all LayerNorms + gates + cell update. Single block, 1024 threads.
// Each thread owns 4 CONSECUTIVE elements (float4-vectorized loads/stores).
// All 10 first-phase reduction values (5 parts x {sum, sumsq}) are reduced
// in one batched pass -> 2 __syncthreads total instead of 24.
// ---------------------------------------------------------------------------
__global__ __launch_bounds__(1024) void epilogue_kernel(
    const float* __restrict__ z, const float* __restrict__ c0,
    const float* __restrict__ c1, const float* __restrict__ ffio_g,
    const float* __restrict__ ffio_b, const float* __restrict__ u_g,
    const float* __restrict__ u_b, const float* __restrict__ c_g,
    const float* __restrict__ c_b, float* __restrict__ out) {
  const int tid = threadIdx.x;   // 0..1023
  const int lane = tid & 63;
  const int wv = tid >> 6;       // 16 waves

  __shared__ float sredA[10][16];
  __shared__ float sredB[2][16];

  const v4f* __restrict__ z4 = (const v4f*)z;

  // Load the 5 z-parts (4 consecutive elems per thread) + per-part partials
  v4f zp[5];
  float vals[10];
#pragma unroll
  for (int p = 0; p < 5; ++p) {
    zp[p] = z4[p * (H / 4) + tid];
    vals[2 * p] = zp[p][0] + zp[p][1] + zp[p][2] + zp[p][3];
    vals[2 * p + 1] = zp[p][0] * zp[p][0] + zp[p][1] * zp[p][1] +
                      zp[p][2] * zp[p][2] + zp[p][3] * zp[p][3];
  }

  // Batched wave reduce of all 10 values, then one barrier
#pragma unroll
  for (int off = 32; off; off >>= 1)
#pragma unroll
    for (int k = 0; k < 10; ++k) vals[k] += __shfl_down(vals[k], off, 64);
  if (lane == 0)
#pragma unroll
    for (int k = 0; k < 10; ++k) sredA[k][wv] = vals[k];
  __syncthreads();

  float mean[5], rstd[5];
#pragma unroll
  for (int p = 0; p < 5; ++p) {
    float s = 0.f, q = 0.f;
#pragma unroll
    for (int w = 0; w < 16; ++w) {
      s += sredA[2 * p][w];      // LDS broadcast reads
      q += sredA[2 * p + 1][w];
    }
    float m = s * (1.0f / H);
    float v = q * (1.0f / H) - m * m;  // jnp.var = E[x^2] - E[x]^2
    mean[p] = m;
    rstd[p] = rsqrtf(v + EPS);
  }

  // Gate params + old cells (float4)
  v4f gg[4], gb[4];
#pragma unroll
  for (int p = 0; p < 4; ++p) {
    gg[p] = ((const v4f*)ffio_g)[p * (H / 4) + tid];
    gb[p] = ((const v4f*)ffio_b)[p * (H / 4) + tid];
  }
  v4f ug = ((const v4f*)u_g)[tid];
  v4f ub = ((const v4f*)u_b)[tid];
  v4f c0v = ((const v4f*)c0)[tid];
  v4f c1v = ((const v4f*)c1)[tid];

  v4f oo, cpre;
#pragma unroll
  for (int j = 0; j < 4; ++j) {
    float n0 = (zp[0][j] - mean[0]) * rstd[0] * gg[0][j] + gb[0][j];
    float n1 = (zp[1][j] - mean[1]) * rstd[1] * gg[1][j] + gb[1][j];
    float n2 = (zp[2][j] - mean[2]) * rstd[2] * gg[2][j] + gb[2][j];
    float n3 = (zp[3][j] - mean[3]) * rstd[3] * gg[3][j] + gb[3][j];
    float n4 = (zp[4][j] - mean[4]) * rstd[4] * ug[j] + ub[j];
    float f0 = 1.f / (1.f + expf(-n0));
    float f1 = 1.f / (1.f + expf(-n1));
    float ig = 1.f / (1.f + expf(-n2));
    oo[j] = 1.f / (1.f + expf(-n3));
    float uu = tanhf(n4);
    cpre[j] = ig * uu + f0 * c0v[j] + f1 * c1v[j];
  }

  // LayerNorm over the new cell: batched 2-value reduction, one barrier
  {
    float s = cpre[0] + cpre[1] + cpre[2] + cpre[3];
    float q = cpre[0] * cpre[0] + cpre[1] * cpre[1] + cpre[2] * cpre[2] +
              cpre[3] * cpre[3];
#pragma unroll
    for (int off = 32; off; off >>= 1) {
      s += __shfl_down(s, off, 64);
      q += __shfl_down(q, off, 64);
    }
    if (lane == 0) {
      sredB[0][wv] = s;
      sredB[1][wv] = q;
    }
    __syncthreads();
    s = 0.f;
    q = 0.f;
#pragma unroll
    for (int w = 0; w < 16; ++w) {
      s += sredB[0][w];
      q += sredB[1][w];
    }
    float m = s * (1.0f / H);
    float v = q * (1.0f / H) - m * m;
    float r = rsqrtf(v + EPS);

    v4f cgv = ((const v4f*)c_g)[tid];
    v4f cbv = ((const v4f*)c_b)[tid];
    v4f cell, hid;
#pragma unroll
    for (int j = 0; j < 4; ++j) {
      cell[j] = (cpre[j] - m) * r * cgv[j] + cbv[j];
      hid[j] = oo[j] * tanhf(cell[j]);
    }
    ((v4f*)out)[(H / 4) + tid] = cell;  // new_cell
    ((v4f*)out)[tid] = hid;             // new_hidden
  }
}

extern "C" void kernel_launch(void* const* d_in, const int* in_sizes, int n_in,
                              void* d_out, int out_size, void* d_ws,
                              size_t ws_size, hipStream_t stream) {
  const float* h0 = (const float*)d_in[0];
  const float* c0 = (const float*)d_in[1];
  const float* h1 = (const float*)d_in[2];
  const float* c1 = (const float*)d_in[3];
  const float* W = (const float*)d_in[4];
  const float* ffio_g = (const float*)d_in[5];
  const float* ffio_b = (const float*)d_in[6];
  const float* u_g = (const float*)d_in[7];
  const float* u_b = (const float*)d_in[8];
  const float* c_g = (const float*)d_in[9];
  const float* c_b = (const float*)d_in[10];
  float* out = (float*)d_out;
  float* z = (float*)d_ws;  // 5H floats = 80 KiB scratch

  // 2560 blocks x 256 threads; each block = 4 waves x 2 rows = 8 rows
  matvec_kernel<<<FIVE_H / 8, 256, 0, stream>>>(W, h0, h1, z);
  epilogue_kernel<<<1, 1024, 0, stream>>>(z, c0, c1, ffio_g, ffio_b, u_g, u_b,
                                          c_g, c_b, out);
}